// Round 2
// baseline (781.845 us; speedup 1.0000x reference)
//
#include <hip/hip_runtime.h>
#include <math.h>

#define NA 2048
#define CP 16
#define NH 4

// ---------------- Kernel 1: LN(ql) + q/k/v/gate projections ----------------
// Coalesced W reads: 32 lanes cover one W row (32 x float4 = 128 floats),
// 2 cols per wave-instruction, shuffle-reduce partials. Wave w owns matrix w.
// k and v are written TRANSPOSED: kT/vT layout [h][c][NA] = [(h*32+c)*NA + j].
__global__ __launch_bounds__(256) void qkvg_kernel(
    const float* __restrict__ ql,
    const float* __restrict__ nqw, const float* __restrict__ nqb,
    const float* __restrict__ Wq, const float* __restrict__ bq,
    const float* __restrict__ Wk, const float* __restrict__ Wv,
    const float* __restrict__ Wg,
    float* __restrict__ q_out, float* __restrict__ kT_out,
    float* __restrict__ vT_out, float* __restrict__ g_out)
{
    __shared__ float x_lds[4 * 128];
    __shared__ float xn_lds[4 * 128];
    const int t = threadIdx.x;
    const int row0 = blockIdx.x * 4;

    for (int idx = t; idx < 512; idx += 256)
        x_lds[idx] = ql[(size_t)row0 * 128 + idx];
    __syncthreads();

    if (t < 128) {
        const int r = t >> 5, id = t & 31;
        const float4 x4 = ((const float4*)x_lds)[r * 32 + id];
        float s = x4.x + x4.y + x4.z + x4.w;
        float s2 = x4.x * x4.x + x4.y * x4.y + x4.z * x4.z + x4.w * x4.w;
#pragma unroll
        for (int m = 16; m >= 1; m >>= 1) {
            s += __shfl_xor(s, m);
            s2 += __shfl_xor(s2, m);
        }
        const float mu = s * (1.0f / 128.0f);
        const float inv = rsqrtf(s2 * (1.0f / 128.0f) - mu * mu + 1e-5f);
#pragma unroll
        for (int k = 0; k < 4; ++k) {
            const int c = id * 4 + k;
            xn_lds[r * 128 + c] = (x_lds[r * 128 + c] - mu) * inv * nqw[c] + nqb[c];
        }
    }
    __syncthreads();

    const int wave = t >> 6, lane = t & 63;
    const int kseg = lane & 31, chalf = lane >> 5;
    const float* W = (wave == 0) ? Wq : (wave == 1) ? Wk : (wave == 2) ? Wv : Wg;
    const float4* xn4 = (const float4*)xn_lds;

    for (int it = 0; it < 64; ++it) {
        const int col = it * 2 + chalf;
        const float4 w4 = *(const float4*)(W + (size_t)col * 128 + kseg * 4);
        float p0, p1, p2, p3;
        {
            float4 a;
            a = xn4[0 * 32 + kseg]; p0 = a.x * w4.x + a.y * w4.y + a.z * w4.z + a.w * w4.w;
            a = xn4[1 * 32 + kseg]; p1 = a.x * w4.x + a.y * w4.y + a.z * w4.z + a.w * w4.w;
            a = xn4[2 * 32 + kseg]; p2 = a.x * w4.x + a.y * w4.y + a.z * w4.z + a.w * w4.w;
            a = xn4[3 * 32 + kseg]; p3 = a.x * w4.x + a.y * w4.y + a.z * w4.z + a.w * w4.w;
        }
#pragma unroll
        for (int m = 16; m >= 1; m >>= 1) {
            p0 += __shfl_xor(p0, m);
            p1 += __shfl_xor(p1, m);
            p2 += __shfl_xor(p2, m);
            p3 += __shfl_xor(p3, m);
        }
        if (kseg == 0) {
            if (wave == 0) {
                const float bb = bq[col];
                const float sc = 0.17677669529663687f; // 1/sqrt(32)
                q_out[(size_t)(row0 + 0) * 128 + col] = (p0 + bb) * sc;
                q_out[(size_t)(row0 + 1) * 128 + col] = (p1 + bb) * sc;
                q_out[(size_t)(row0 + 2) * 128 + col] = (p2 + bb) * sc;
                q_out[(size_t)(row0 + 3) * 128 + col] = (p3 + bb) * sc;
            } else if (wave == 1) {
                float4 o; o.x = p0; o.y = p1; o.z = p2; o.w = p3;
                *(float4*)(kT_out + (size_t)col * NA + row0) = o;
            } else if (wave == 2) {
                float4 o; o.x = p0; o.y = p1; o.z = p2; o.w = p3;
                *(float4*)(vT_out + (size_t)col * NA + row0) = o;
            } else {
                g_out[(size_t)(row0 + 0) * 128 + col] = 1.0f / (1.0f + __expf(-p0));
                g_out[(size_t)(row0 + 1) * 128 + col] = 1.0f / (1.0f + __expf(-p1));
                g_out[(size_t)(row0 + 2) * 128 + col] = 1.0f / (1.0f + __expf(-p2));
                g_out[(size_t)(row0 + 3) * 128 + col] = 1.0f / (1.0f + __expf(-p3));
            }
        }
    }
}

// ---------------- Kernel 2: pair bias + attention, 2 query rows / block ----
// Wave h owns head h for both rows. kT/vT give fully-coalesced j-major reads.
__global__ __launch_bounds__(256) void attn_kernel(
    const float* __restrict__ plm, const float* __restrict__ beta_mask,
    const float* __restrict__ npw, const float* __restrict__ npb,
    const float* __restrict__ Wpb,
    const float* __restrict__ q_ws, const float* __restrict__ kT,
    const float* __restrict__ vT, const float* __restrict__ g_ws,
    float* __restrict__ attn_g)
{
    __shared__ float logit[2][NH][NA];   // 64 KiB -> 2 blocks/CU
    __shared__ float qs[2][128];
    __shared__ float wpb_s[64];
    __shared__ float npw_s[16], npb_s[16];

    const int t = threadIdx.x;
    const int i0 = blockIdx.x * 2;
    const int h = t >> 6;
    const int lane = t & 63;

    {
        const int r = t >> 7, c = t & 127;
        qs[r][c] = q_ws[(size_t)(i0 + r) * 128 + c];
    }
    if (t < 64) wpb_s[t] = Wpb[t];
    if (t < 16) { npw_s[t] = npw[t]; npb_s[t] = npb[t]; }
    __syncthreads();

    // Phase A: pair-bias LN + Wpb proj + beta_mask -> logit
#pragma unroll
    for (int r = 0; r < 2; ++r) {
        const size_t prow = (size_t)(i0 + r) * NA * CP;
        const size_t brow = (size_t)(i0 + r) * NA;
        for (int j = t; j < NA; j += 256) {
            const float4* p4 = (const float4*)(plm + prow + (size_t)j * CP);
            const float4 A = p4[0], B = p4[1], C = p4[2], D = p4[3];
            float xv[16] = {A.x, A.y, A.z, A.w, B.x, B.y, B.z, B.w,
                            C.x, C.y, C.z, C.w, D.x, D.y, D.z, D.w};
            float s = 0.0f, s2 = 0.0f;
#pragma unroll
            for (int k = 0; k < 16; ++k) { s += xv[k]; s2 += xv[k] * xv[k]; }
            const float mu = s * (1.0f / 16.0f);
            const float inv = rsqrtf(s2 * (1.0f / 16.0f) - mu * mu + 1e-5f);
            float xn[16];
#pragma unroll
            for (int k = 0; k < 16; ++k) xn[k] = (xv[k] - mu) * inv * npw_s[k] + npb_s[k];
            const float bm = beta_mask[brow + j];
#pragma unroll
            for (int hh = 0; hh < 4; ++hh) {
                float b = bm;
#pragma unroll
                for (int k = 0; k < 16; ++k) b += xn[k] * wpb_s[hh * 16 + k];
                logit[r][hh][j] = b;
            }
        }
    }
    __syncthreads();

    // Phase B: logits += q.k via kT (coalesced over j)
    float q0[32], q1[32];
#pragma unroll
    for (int c = 0; c < 32; ++c) {
        q0[c] = qs[0][h * 32 + c];
        q1[c] = qs[1][h * 32 + c];
    }
    float4* L0 = (float4*)&logit[0][h][0];
    float4* L1 = (float4*)&logit[1][h][0];
    const float* kbase = kT + (size_t)(h * 32) * NA;
#pragma unroll 1
    for (int tile = 0; tile < 8; ++tile) {
        const int jv = tile * 64 + lane;            // float4 index in row
        const float* kp = kbase + (size_t)jv * 4;
        float4 a0 = {0, 0, 0, 0}, a1 = {0, 0, 0, 0};
#pragma unroll
        for (int c = 0; c < 32; ++c) {
            const float4 k4 = *(const float4*)(kp + (size_t)c * NA);
            a0.x += q0[c] * k4.x; a0.y += q0[c] * k4.y;
            a0.z += q0[c] * k4.z; a0.w += q0[c] * k4.w;
            a1.x += q1[c] * k4.x; a1.y += q1[c] * k4.y;
            a1.z += q1[c] * k4.z; a1.w += q1[c] * k4.w;
        }
        float4 l0 = L0[jv];
        l0.x += a0.x; l0.y += a0.y; l0.z += a0.z; l0.w += a0.w;
        L0[jv] = l0;
        float4 l1 = L1[jv];
        l1.x += a1.x; l1.y += a1.y; l1.z += a1.z; l1.w += a1.w;
        L1[jv] = l1;
    }

    // Softmax (two-pass, full row in LDS), per head per row
    float invl[2];
#pragma unroll
    for (int r = 0; r < 2; ++r) {
        float4* Lr = (r == 0) ? L0 : L1;
        float m = -3.4e38f;
#pragma unroll
        for (int it = 0; it < 8; ++it) {
            const float4 x = Lr[it * 64 + lane];
            m = fmaxf(m, fmaxf(fmaxf(x.x, x.y), fmaxf(x.z, x.w)));
        }
#pragma unroll
        for (int mk = 32; mk >= 1; mk >>= 1) m = fmaxf(m, __shfl_xor(m, mk));
        float s = 0.0f;
#pragma unroll
        for (int it = 0; it < 8; ++it) {
            float4 x = Lr[it * 64 + lane];
            x.x = __expf(x.x - m); x.y = __expf(x.y - m);
            x.z = __expf(x.z - m); x.w = __expf(x.w - m);
            s += x.x + x.y + x.z + x.w;
            Lr[it * 64 + lane] = x;
        }
#pragma unroll
        for (int mk = 32; mk >= 1; mk >>= 1) s += __shfl_xor(s, mk);
        invl[r] = 1.0f / s;
    }

    // Phase C: O = P.V via vT (coalesced over j), per-lane partials over j
    float o0[32], o1[32];
#pragma unroll
    for (int c = 0; c < 32; ++c) { o0[c] = 0.0f; o1[c] = 0.0f; }
    const float* vbase = vT + (size_t)(h * 32) * NA;
#pragma unroll 1
    for (int tile = 0; tile < 8; ++tile) {
        const int jv = tile * 64 + lane;
        const float4 p0 = L0[jv];
        const float4 p1 = L1[jv];
        const float* vp = vbase + (size_t)jv * 4;
#pragma unroll
        for (int c = 0; c < 32; ++c) {
            const float4 v4 = *(const float4*)(vp + (size_t)c * NA);
            o0[c] += p0.x * v4.x + p0.y * v4.y + p0.z * v4.z + p0.w * v4.w;
            o1[c] += p1.x * v4.x + p1.y * v4.y + p1.z * v4.z + p1.w * v4.w;
        }
    }
    // reduce each channel across 64 lanes; lane c keeps channel c
    float r0 = 0.0f, r1 = 0.0f;
#pragma unroll
    for (int c = 0; c < 32; ++c) {
        float s0 = o0[c], s1 = o1[c];
#pragma unroll
        for (int mk = 32; mk >= 1; mk >>= 1) {
            s0 += __shfl_xor(s0, mk);
            s1 += __shfl_xor(s1, mk);
        }
        if (lane == c) { r0 = s0; r1 = s1; }
    }
    if (lane < 32) {
        const int c = h * 32 + lane;
        const float g0 = g_ws[(size_t)i0 * 128 + c];
        const float g1 = g_ws[(size_t)(i0 + 1) * 128 + c];
        attn_g[(size_t)i0 * 128 + c] = r0 * invl[0] * g0;
        attn_g[(size_t)(i0 + 1) * 128 + c] = r1 * invl[1] * g1;
    }
}

// ---------------- Kernel 3: Wo proj + residual + LN + MLP + residual -------
__global__ __launch_bounds__(256) void out_mlp_kernel(
    const float* __restrict__ ql,
    const float* __restrict__ attn_g,
    const float* __restrict__ Wo,
    const float* __restrict__ tlw, const float* __restrict__ tlb,
    const float* __restrict__ W1, const float* __restrict__ b1,
    const float* __restrict__ W2, const float* __restrict__ b2,
    float* __restrict__ out)
{
    __shared__ float a_lds[4 * 128];
    __shared__ float ql2_lds[4 * 128];
    __shared__ float t_lds[4 * 128];
    __shared__ float h1_lds[4 * 512];
    const int t = threadIdx.x;
    const int row0 = blockIdx.x * 4;

    for (int idx = t; idx < 512; idx += 256)
        a_lds[idx] = attn_g[(size_t)row0 * 128 + idx];
    __syncthreads();

    const int wave = t >> 6, lane = t & 63;
    const int kseg = lane & 31, chalf = lane >> 5;
    const float4* a4 = (const float4*)a_lds;

    // Stage 1: ql2 = ql + gated_attn @ Wo.T  (128 cols, 32 per wave)
    for (int it = 0; it < 16; ++it) {
        const int col = wave * 32 + it * 2 + chalf;
        const float4 w4 = *(const float4*)(Wo + (size_t)col * 128 + kseg * 4);
        float p[4];
#pragma unroll
        for (int r = 0; r < 4; ++r) {
            const float4 a = a4[r * 32 + kseg];
            p[r] = a.x * w4.x + a.y * w4.y + a.z * w4.z + a.w * w4.w;
        }
#pragma unroll
        for (int mk = 16; mk >= 1; mk >>= 1) {
#pragma unroll
            for (int r = 0; r < 4; ++r) p[r] += __shfl_xor(p[r], mk);
        }
        if (kseg == 0) {
#pragma unroll
            for (int r = 0; r < 4; ++r)
                ql2_lds[r * 128 + col] = ql[(size_t)(row0 + r) * 128 + col] + p[r];
        }
    }
    __syncthreads();

    // LayerNorm(ql2) -> t_lds
    if (t < 128) {
        const int r = t >> 5, id = t & 31;
        const float4 x4 = ((const float4*)ql2_lds)[r * 32 + id];
        float s = x4.x + x4.y + x4.z + x4.w;
        float s2 = x4.x * x4.x + x4.y * x4.y + x4.z * x4.z + x4.w * x4.w;
#pragma unroll
        for (int m = 16; m >= 1; m >>= 1) {
            s += __shfl_xor(s, m);
            s2 += __shfl_xor(s2, m);
        }
        const float mu = s * (1.0f / 128.0f);
        const float inv = rsqrtf(s2 * (1.0f / 128.0f) - mu * mu + 1e-5f);
#pragma unroll
        for (int k = 0; k < 4; ++k) {
            const int c = id * 4 + k;
            t_lds[r * 128 + c] = (ql2_lds[r * 128 + c] - mu) * inv * tlw[c] + tlb[c];
        }
    }
    __syncthreads();

    // Stage 2: h1 = relu(t @ W1.T + b1)  (512 cols, 128 per wave)
    const float4* t4 = (const float4*)t_lds;
    for (int it = 0; it < 64; ++it) {
        const int col = wave * 128 + it * 2 + chalf;
        const float4 w4 = *(const float4*)(W1 + (size_t)col * 128 + kseg * 4);
        float p[4];
#pragma unroll
        for (int r = 0; r < 4; ++r) {
            const float4 a = t4[r * 32 + kseg];
            p[r] = a.x * w4.x + a.y * w4.y + a.z * w4.z + a.w * w4.w;
        }
#pragma unroll
        for (int mk = 16; mk >= 1; mk >>= 1) {
#pragma unroll
            for (int r = 0; r < 4; ++r) p[r] += __shfl_xor(p[r], mk);
        }
        if (kseg == 0) {
            const float bb = b1[col];
#pragma unroll
            for (int r = 0; r < 4; ++r)
                h1_lds[r * 512 + col] = fmaxf(p[r] + bb, 0.0f);
        }
    }
    __syncthreads();

    // Stage 3: out = ql2 + h1 @ W2.T + b2  (128 cols, K=512; 64 lanes per col)
    const float4* h4 = (const float4*)h1_lds;
    for (int it = 0; it < 32; ++it) {
        const int col = wave * 32 + it;
        float p[4] = {0, 0, 0, 0};
#pragma unroll
        for (int half = 0; half < 2; ++half) {
            const float4 w4 = *(const float4*)(W2 + (size_t)col * 512 + half * 256 + lane * 4);
#pragma unroll
            for (int r = 0; r < 4; ++r) {
                const float4 hh = h4[r * 128 + half * 64 + lane];
                p[r] += hh.x * w4.x + hh.y * w4.y + hh.z * w4.z + hh.w * w4.w;
            }
        }
#pragma unroll
        for (int mk = 32; mk >= 1; mk >>= 1) {
#pragma unroll
            for (int r = 0; r < 4; ++r) p[r] += __shfl_xor(p[r], mk);
        }
        if (lane == 0) {
            const float bb = b2[col];
#pragma unroll
            for (int r = 0; r < 4; ++r)
                out[(size_t)(row0 + r) * 128 + col] = ql2_lds[r * 128 + col] + p[r] + bb;
        }
    }
}

extern "C" void kernel_launch(void* const* d_in, const int* in_sizes, int n_in,
                              void* d_out, int out_size, void* d_ws, size_t ws_size,
                              hipStream_t stream) {
    const float* ql   = (const float*)d_in[0];
    // d_in[1] = cl : unused by the reference
    const float* plm  = (const float*)d_in[2];
    const float* beta = (const float*)d_in[3];
    const float* nqw  = (const float*)d_in[4];
    const float* nqb  = (const float*)d_in[5];
    const float* npw  = (const float*)d_in[6];
    const float* npb  = (const float*)d_in[7];
    const float* Wq   = (const float*)d_in[8];
    const float* bq   = (const float*)d_in[9];
    const float* Wk   = (const float*)d_in[10];
    const float* Wv   = (const float*)d_in[11];
    const float* Wpb  = (const float*)d_in[12];
    const float* Wg   = (const float*)d_in[13];
    const float* Wo   = (const float*)d_in[14];
    const float* tlw  = (const float*)d_in[15];
    const float* tlb  = (const float*)d_in[16];
    const float* W1   = (const float*)d_in[17];
    const float* b1   = (const float*)d_in[18];
    const float* W2   = (const float*)d_in[19];
    const float* b2   = (const float*)d_in[20];
    float* out = (float*)d_out;

    float* ws = (float*)d_ws;
    float* q_ws  = ws;
    float* g_ws  = ws + 1 * 262144;
    float* kT_ws = ws + 2 * 262144;
    float* vT_ws = ws + 3 * 262144;
    float* ag_ws = ws + 4 * 262144;

    qkvg_kernel<<<NA / 4, 256, 0, stream>>>(ql, nqw, nqb, Wq, bq, Wk, Wv, Wg,
                                            q_ws, kT_ws, vT_ws, g_ws);
    attn_kernel<<<NA / 2, 256, 0, stream>>>(plm, beta, npw, npb, Wpb,
                                            q_ws, kT_ws, vT_ws, g_ws, ag_ws);
    out_mlp_kernel<<<NA / 4, 256, 0, stream>>>(ql, ag_ws, Wo, tlw, tlb,
                                               W1, b1, W2, b2, out);
}

// Round 3
// 532.949 us; speedup vs baseline: 1.4670x; 1.4670x over previous
//
#include <hip/hip_runtime.h>
#include <hip/hip_bf16.h>
#include <math.h>

#define NA 2048
#define CP 16

// ===== Kernel A: stream plm -> bias[h][i][j] = LN(plm)@Wpb.T + beta (bf16) =====
// 4 lanes per j (one per channel-quad == one per head). Fully-coalesced b128 plm
// reads (wave covers 1 KB contiguous). Zero LDS, grid 8192 -> deep latency hiding.
__global__ __launch_bounds__(256) void bias_kernel(
    const float* __restrict__ plm, const float* __restrict__ beta_mask,
    const float* __restrict__ npw, const float* __restrict__ npb,
    const float* __restrict__ Wpb,
    __hip_bfloat16* __restrict__ biasT)
{
    const int t = threadIdx.x;
    const int quad = t & 3;            // channel-quad AND head id for the write
    const int jloc = t >> 2;           // 0..63
    const int jc = blockIdx.x & 31;
    const int ic = blockIdx.x >> 5;
    const int j = jc * 64 + jloc;
    const int i0 = ic * 8;

    float w0[4], w1[4], w2[4], w3[4];
    {
        const float4 a = *(const float4*)(Wpb + 0 * 16 + quad * 4);
        w0[0] = a.x; w0[1] = a.y; w0[2] = a.z; w0[3] = a.w;
        const float4 b = *(const float4*)(Wpb + 1 * 16 + quad * 4);
        w1[0] = b.x; w1[1] = b.y; w1[2] = b.z; w1[3] = b.w;
        const float4 c = *(const float4*)(Wpb + 2 * 16 + quad * 4);
        w2[0] = c.x; w2[1] = c.y; w2[2] = c.z; w2[3] = c.w;
        const float4 d = *(const float4*)(Wpb + 3 * 16 + quad * 4);
        w3[0] = d.x; w3[1] = d.y; w3[2] = d.z; w3[3] = d.w;
    }
    const float4 nw = *(const float4*)(npw + quad * 4);
    const float4 nb = *(const float4*)(npb + quad * 4);

#pragma unroll
    for (int ii = 0; ii < 8; ++ii) {
        const int i = i0 + ii;
        const float4 x = *(const float4*)(plm + ((size_t)i * NA + j) * CP + quad * 4);
        float s = x.x + x.y + x.z + x.w;
        float s2 = x.x * x.x + x.y * x.y + x.z * x.z + x.w * x.w;
        s += __shfl_xor(s, 1); s2 += __shfl_xor(s2, 1);
        s += __shfl_xor(s, 2); s2 += __shfl_xor(s2, 2);
        const float mu = s * 0.0625f;
        const float inv = rsqrtf(s2 * 0.0625f - mu * mu + 1e-5f);
        const float x0 = (x.x - mu) * inv * nw.x + nb.x;
        const float x1 = (x.y - mu) * inv * nw.y + nb.y;
        const float x2 = (x.z - mu) * inv * nw.z + nb.z;
        const float x3 = (x.w - mu) * inv * nw.w + nb.w;
        float p0 = x0 * w0[0] + x1 * w0[1] + x2 * w0[2] + x3 * w0[3];
        float p1 = x0 * w1[0] + x1 * w1[1] + x2 * w1[2] + x3 * w1[3];
        float p2 = x0 * w2[0] + x1 * w2[1] + x2 * w2[2] + x3 * w2[3];
        float p3 = x0 * w3[0] + x1 * w3[1] + x2 * w3[2] + x3 * w3[3];
        p0 += __shfl_xor(p0, 1); p1 += __shfl_xor(p1, 1);
        p2 += __shfl_xor(p2, 1); p3 += __shfl_xor(p3, 1);
        p0 += __shfl_xor(p0, 2); p1 += __shfl_xor(p1, 2);
        p2 += __shfl_xor(p2, 2); p3 += __shfl_xor(p3, 2);
        const float bm = beta_mask[(size_t)i * NA + j];
        const float sel = (quad == 0) ? p0 : (quad == 1) ? p1 : (quad == 2) ? p2 : p3;
        biasT[(size_t)quad * NA * NA + (size_t)i * NA + j] = __float2bfloat16(sel + bm);
    }
}

// ===== Kernel 1: LN(ql) + q/k/v/gate projections =====
__global__ __launch_bounds__(256) void qkvg_kernel(
    const float* __restrict__ ql,
    const float* __restrict__ nqw, const float* __restrict__ nqb,
    const float* __restrict__ Wq, const float* __restrict__ bq,
    const float* __restrict__ Wk, const float* __restrict__ Wv,
    const float* __restrict__ Wg,
    float* __restrict__ q_out, float* __restrict__ kT_out,
    float* __restrict__ vT_out, float* __restrict__ g_out)
{
    __shared__ float x_lds[4 * 128];
    __shared__ float xn_lds[4 * 128];
    const int t = threadIdx.x;
    const int row0 = blockIdx.x * 4;

    for (int idx = t; idx < 512; idx += 256)
        x_lds[idx] = ql[(size_t)row0 * 128 + idx];
    __syncthreads();

    if (t < 128) {
        const int r = t >> 5, id = t & 31;
        const float4 x4 = ((const float4*)x_lds)[r * 32 + id];
        float s = x4.x + x4.y + x4.z + x4.w;
        float s2 = x4.x * x4.x + x4.y * x4.y + x4.z * x4.z + x4.w * x4.w;
#pragma unroll
        for (int m = 16; m >= 1; m >>= 1) {
            s += __shfl_xor(s, m);
            s2 += __shfl_xor(s2, m);
        }
        const float mu = s * (1.0f / 128.0f);
        const float inv = rsqrtf(s2 * (1.0f / 128.0f) - mu * mu + 1e-5f);
#pragma unroll
        for (int k = 0; k < 4; ++k) {
            const int c = id * 4 + k;
            xn_lds[r * 128 + c] = (x_lds[r * 128 + c] - mu) * inv * nqw[c] + nqb[c];
        }
    }
    __syncthreads();

    const float4* xn4 = (const float4*)xn_lds;
#pragma unroll
    for (int cc = 0; cc < 2; ++cc) {
        const int col = cc * 256 + t;
        const int m = col >> 7;        // wave-uniform
        const int cl = col & 127;
        const float* W = (m == 0) ? Wq : (m == 1) ? Wk : (m == 2) ? Wv : Wg;
        float acc[4] = {0, 0, 0, 0};
        const float4* wrow = (const float4*)(W + (size_t)cl * 128);
#pragma unroll 8
        for (int k4 = 0; k4 < 32; ++k4) {
            const float4 w4 = wrow[k4];
#pragma unroll
            for (int r = 0; r < 4; ++r) {
                const float4 a = xn4[r * 32 + k4];
                acc[r] += a.x * w4.x + a.y * w4.y + a.z * w4.z + a.w * w4.w;
            }
        }
        if (m == 0) {
            const float bb = bq[cl];
            const float sc = 0.17677669529663687f; // 1/sqrt(32)
#pragma unroll
            for (int r = 0; r < 4; ++r)
                q_out[(size_t)(row0 + r) * 128 + cl] = (acc[r] + bb) * sc;
        } else if (m == 1) {
            float4 o; o.x = acc[0]; o.y = acc[1]; o.z = acc[2]; o.w = acc[3];
            *(float4*)(kT_out + (size_t)cl * NA + row0) = o;
        } else if (m == 2) {
            float4 o; o.x = acc[0]; o.y = acc[1]; o.z = acc[2]; o.w = acc[3];
            *(float4*)(vT_out + (size_t)cl * NA + row0) = o;
        } else {
#pragma unroll
            for (int r = 0; r < 4; ++r)
                g_out[(size_t)(row0 + r) * 128 + cl] = 1.0f / (1.0f + __expf(-acc[r]));
        }
    }
}

// ===== Kernel B: attention. Block = (head, 8 rows). Waves j-split (512 j each).
// Logits in VGPRs; bias precomputed; k/v coalesced from L2 once per block. =====
__global__ __launch_bounds__(256) void attn_kernel(
    const __hip_bfloat16* __restrict__ biasT,
    const float* __restrict__ q_ws, const float* __restrict__ kT,
    const float* __restrict__ vT, const float* __restrict__ g_ws,
    float* __restrict__ attn_g)
{
    __shared__ unsigned short Lp[8][2048];   // p (scaled) bf16: 32 KB
    __shared__ float q_s[8 * 32];
    __shared__ float redA[4 * 8];
    __shared__ float redB[4 * 8];
    __shared__ float opart[4 * 8 * 32];

    const int t = threadIdx.x;
    const int h = blockIdx.x & 3;
    const int i0 = (blockIdx.x >> 2) * 8;
    const int w = t >> 6, lane = t & 63;
    const int jq = w * 512;

    q_s[t] = q_ws[(size_t)(i0 + (t >> 5)) * 128 + h * 32 + (t & 31)];
    __syncthreads();

    // init logits from bias(+beta)
    float4 La[8], Lb[8];
#pragma unroll
    for (int r = 0; r < 8; ++r) {
        const __hip_bfloat16* base = biasT + (size_t)h * NA * NA + (size_t)(i0 + r) * NA;
        const __hip_bfloat162* ba = (const __hip_bfloat162*)(base + jq + lane * 4);
        const float2 f0 = __bfloat1622float2(ba[0]);
        const float2 f1 = __bfloat1622float2(ba[1]);
        La[r] = make_float4(f0.x, f0.y, f1.x, f1.y);
        const __hip_bfloat162* bb = (const __hip_bfloat162*)(base + jq + 256 + lane * 4);
        const float2 g0 = __bfloat1622float2(bb[0]);
        const float2 g1 = __bfloat1622float2(bb[1]);
        Lb[r] = make_float4(g0.x, g0.y, g1.x, g1.y);
    }

    // QK: logits += q . k  (kT coalesced over j; q broadcast from LDS)
    const float* kb = kT + (size_t)(h * 32) * NA + jq + lane * 4;
#pragma unroll 4
    for (int c = 0; c < 32; ++c) {
        const float4 ka = *(const float4*)(kb + (size_t)c * NA);
        const float4 kc = *(const float4*)(kb + (size_t)c * NA + 256);
#pragma unroll
        for (int r = 0; r < 8; ++r) {
            const float qv = q_s[r * 32 + c];
            La[r].x += qv * ka.x; La[r].y += qv * ka.y;
            La[r].z += qv * ka.z; La[r].w += qv * ka.w;
            Lb[r].x += qv * kc.x; Lb[r].y += qv * kc.y;
            Lb[r].z += qv * kc.z; Lb[r].w += qv * kc.w;
        }
    }

    // softmax: wave-partial max -> combine -> exp -> wave-partial sum -> combine
#pragma unroll
    for (int r = 0; r < 8; ++r) {
        float m = fmaxf(fmaxf(fmaxf(La[r].x, La[r].y), fmaxf(La[r].z, La[r].w)),
                        fmaxf(fmaxf(Lb[r].x, Lb[r].y), fmaxf(Lb[r].z, Lb[r].w)));
#pragma unroll
        for (int mk = 32; mk >= 1; mk >>= 1) m = fmaxf(m, __shfl_xor(m, mk));
        if (lane == 0) redA[w * 8 + r] = m;
    }
    __syncthreads();
#pragma unroll
    for (int r = 0; r < 8; ++r) {
        const float m = fmaxf(fmaxf(redA[r], redA[8 + r]), fmaxf(redA[16 + r], redA[24 + r]));
        La[r].x = __expf(La[r].x - m); La[r].y = __expf(La[r].y - m);
        La[r].z = __expf(La[r].z - m); La[r].w = __expf(La[r].w - m);
        Lb[r].x = __expf(Lb[r].x - m); Lb[r].y = __expf(Lb[r].y - m);
        Lb[r].z = __expf(Lb[r].z - m); Lb[r].w = __expf(Lb[r].w - m);
        float s = La[r].x + La[r].y + La[r].z + La[r].w +
                  Lb[r].x + Lb[r].y + Lb[r].z + Lb[r].w;
#pragma unroll
        for (int mk = 32; mk >= 1; mk >>= 1) s += __shfl_xor(s, mk);
        if (lane == 0) redB[w * 8 + r] = s;
    }
    __syncthreads();
#pragma unroll
    for (int r = 0; r < 8; ++r) {
        const float invl = 1.0f / (redB[r] + redB[8 + r] + redB[16 + r] + redB[24 + r]);
        __hip_bfloat162* d = (__hip_bfloat162*)&Lp[r][jq + lane * 4];
        d[0] = __float22bfloat162_rn(make_float2(La[r].x * invl, La[r].y * invl));
        d[1] = __float22bfloat162_rn(make_float2(La[r].z * invl, La[r].w * invl));
        __hip_bfloat162* d2 = (__hip_bfloat162*)&Lp[r][jq + 256 + lane * 4];
        d2[0] = __float22bfloat162_rn(make_float2(Lb[r].x * invl, Lb[r].y * invl));
        d2[1] = __float22bfloat162_rn(make_float2(Lb[r].z * invl, Lb[r].w * invl));
    }
    __syncthreads();

    // PV: lane = (channel c, j-half); vT coalesced; p broadcast from LDS
    const int c = lane & 31, jh = lane >> 5;
    const int jb = jq + jh * 256;
    const float* vbase = vT + (size_t)(h * 32 + c) * NA + jb;
    float o[8] = {0, 0, 0, 0, 0, 0, 0, 0};
#pragma unroll 4
    for (int jf = 0; jf < 64; ++jf) {
        const float4 v4 = *(const float4*)(vbase + jf * 4);
#pragma unroll
        for (int r = 0; r < 8; ++r) {
            const __hip_bfloat162* pp = (const __hip_bfloat162*)&Lp[r][jb + jf * 4];
            const float2 pa = __bfloat1622float2(pp[0]);
            const float2 pb = __bfloat1622float2(pp[1]);
            o[r] += pa.x * v4.x + pa.y * v4.y + pb.x * v4.z + pb.y * v4.w;
        }
    }
#pragma unroll
    for (int r = 0; r < 8; ++r) {
        o[r] += __shfl_xor(o[r], 32);
        if (lane < 32) opart[w * 256 + r * 32 + c] = o[r];
    }
    __syncthreads();
    {
        const int r = t >> 5, cc = t & 31;
        const float val = opart[r * 32 + cc] + opart[256 + r * 32 + cc] +
                          opart[512 + r * 32 + cc] + opart[768 + r * 32 + cc];
        const float g = g_ws[(size_t)(i0 + r) * 128 + h * 32 + cc];
        attn_g[(size_t)(i0 + r) * 128 + h * 32 + cc] = val * g;
    }
}

// ===== Kernel 3: Wo proj + residual + LN + MLP + residual =====
__global__ __launch_bounds__(256) void out_mlp_kernel(
    const float* __restrict__ ql,
    const float* __restrict__ attn_g,
    const float* __restrict__ Wo,
    const float* __restrict__ tlw, const float* __restrict__ tlb,
    const float* __restrict__ W1, const float* __restrict__ b1,
    const float* __restrict__ W2, const float* __restrict__ b2,
    float* __restrict__ out)
{
    __shared__ float a_lds[4 * 128];
    __shared__ float ql2_lds[4 * 128];
    __shared__ float t_lds[4 * 128];
    __shared__ float h1_lds[4 * 512];
    const int t = threadIdx.x;
    const int row0 = blockIdx.x * 4;

    for (int idx = t; idx < 512; idx += 256)
        a_lds[idx] = attn_g[(size_t)row0 * 128 + idx];
    __syncthreads();

    // Stage 1: ql2 = ql + a @ Wo.T ; col = t/2, k-half = t&1
    {
        const int col = t >> 1, kh = t & 1;
        float p[4] = {0, 0, 0, 0};
        const float4* wr = (const float4*)(Wo + (size_t)col * 128 + kh * 64);
        const float4* a4 = (const float4*)a_lds;
#pragma unroll 8
        for (int k4 = 0; k4 < 16; ++k4) {
            const float4 w4 = wr[k4];
#pragma unroll
            for (int r = 0; r < 4; ++r) {
                const float4 a = a4[r * 32 + kh * 16 + k4];
                p[r] += a.x * w4.x + a.y * w4.y + a.z * w4.z + a.w * w4.w;
            }
        }
#pragma unroll
        for (int r = 0; r < 4; ++r) p[r] += __shfl_xor(p[r], 1);
        if (kh == 0) {
#pragma unroll
            for (int r = 0; r < 4; ++r)
                ql2_lds[r * 128 + col] = ql[(size_t)(row0 + r) * 128 + col] + p[r];
        }
    }
    __syncthreads();

    // LayerNorm(ql2) -> t_lds
    if (t < 128) {
        const int r = t >> 5, id = t & 31;
        const float4 x4 = ((const float4*)ql2_lds)[r * 32 + id];
        float s = x4.x + x4.y + x4.z + x4.w;
        float s2 = x4.x * x4.x + x4.y * x4.y + x4.z * x4.z + x4.w * x4.w;
#pragma unroll
        for (int m = 16; m >= 1; m >>= 1) {
            s += __shfl_xor(s, m);
            s2 += __shfl_xor(s2, m);
        }
        const float mu = s * (1.0f / 128.0f);
        const float inv = rsqrtf(s2 * (1.0f / 128.0f) - mu * mu + 1e-5f);
#pragma unroll
        for (int k = 0; k < 4; ++k) {
            const int c = id * 4 + k;
            t_lds[r * 128 + c] = (ql2_lds[r * 128 + c] - mu) * inv * tlw[c] + tlb[c];
        }
    }
    __syncthreads();

    // Stage 2: h1 = relu(t @ W1.T + b1), 2 cols/thread, full K
    const float4* t4 = (const float4*)t_lds;
#pragma unroll
    for (int cc = 0; cc < 2; ++cc) {
        const int col = cc * 256 + t;
        float acc[4] = {0, 0, 0, 0};
        const float4* wr = (const float4*)(W1 + (size_t)col * 128);
#pragma unroll 8
        for (int k4 = 0; k4 < 32; ++k4) {
            const float4 w4 = wr[k4];
#pragma unroll
            for (int r = 0; r < 4; ++r) {
                const float4 a = t4[r * 32 + k4];
                acc[r] += a.x * w4.x + a.y * w4.y + a.z * w4.z + a.w * w4.w;
            }
        }
        const float bb = b1[col];
#pragma unroll
        for (int r = 0; r < 4; ++r)
            h1_lds[r * 512 + col] = fmaxf(acc[r] + bb, 0.0f);
    }
    __syncthreads();

    // Stage 3: out = ql2 + h1 @ W2.T + b2 ; col = t/2, k-half = t&1 (K=512)
    {
        const int col = t >> 1, kh = t & 1;
        float p[4] = {0, 0, 0, 0};
        const float4* wr = (const float4*)(W2 + (size_t)col * 512 + kh * 256);
        const float4* h4 = (const float4*)h1_lds;
#pragma unroll 8
        for (int k4 = 0; k4 < 64; ++k4) {
            const float4 w4 = wr[k4];
#pragma unroll
            for (int r = 0; r < 4; ++r) {
                const float4 a = h4[r * 128 + kh * 64 + k4];
                p[r] += a.x * w4.x + a.y * w4.y + a.z * w4.z + a.w * w4.w;
            }
        }
#pragma unroll
        for (int r = 0; r < 4; ++r) p[r] += __shfl_xor(p[r], 1);
        if (kh == 0) {
            const float bb = b2[col];
#pragma unroll
            for (int r = 0; r < 4; ++r)
                out[(size_t)(row0 + r) * 128 + col] = ql2_lds[r * 128 + col] + p[r] + bb;
        }
    }
}

extern "C" void kernel_launch(void* const* d_in, const int* in_sizes, int n_in,
                              void* d_out, int out_size, void* d_ws, size_t ws_size,
                              hipStream_t stream) {
    const float* ql   = (const float*)d_in[0];
    // d_in[1] = cl : unused by the reference
    const float* plm  = (const float*)d_in[2];
    const float* beta = (const float*)d_in[3];
    const float* nqw  = (const float*)d_in[4];
    const float* nqb  = (const float*)d_in[5];
    const float* npw  = (const float*)d_in[6];
    const float* npb  = (const float*)d_in[7];
    const float* Wq   = (const float*)d_in[8];
    const float* bq   = (const float*)d_in[9];
    const float* Wk   = (const float*)d_in[10];
    const float* Wv   = (const float*)d_in[11];
    const float* Wpb  = (const float*)d_in[12];
    const float* Wg   = (const float*)d_in[13];
    const float* Wo   = (const float*)d_in[14];
    const float* tlw  = (const float*)d_in[15];
    const float* tlb  = (const float*)d_in[16];
    const float* W1   = (const float*)d_in[17];
    const float* b1   = (const float*)d_in[18];
    const float* W2   = (const float*)d_in[19];
    const float* b2   = (const float*)d_in[20];
    float* out = (float*)d_out;

    // workspace layout (bytes): bias bf16 33.5 MB, then 5 fp32 1-MB buffers
    char* ws = (char*)d_ws;
    __hip_bfloat16* biasT = (__hip_bfloat16*)ws;                  // 4*2048*2048*2
    float* q_ws  = (float*)(ws + 33554432);
    float* g_ws  = (float*)(ws + 33554432 + 1 * 1048576);
    float* kT_ws = (float*)(ws + 33554432 + 2 * 1048576);
    float* vT_ws = (float*)(ws + 33554432 + 3 * 1048576);
    float* ag_ws = (float*)(ws + 33554432 + 4 * 1048576);

    bias_kernel<<<8192, 256, 0, stream>>>(plm, beta, npw, npb, Wpb, biasT);
    qkvg_kernel<<<NA / 4, 256, 0, stream>>>(ql, nqw, nqb, Wq, bq, Wk, Wv, Wg,
                                            q_ws, kT_ws, vT_ws, g_ws);
    attn_kernel<<<NA / 2, 256, 0, stream>>>(biasT, q_ws, kT_ws, vT_ws, g_ws, ag_ws);
    out_mlp_kernel<<<NA / 4, 256, 0, stream>>>(ql, ag_ws, Wo, tlw, tlb,
                                               W1, b1, W2, b2, out);
}

// Round 4
// 531.256 us; speedup vs baseline: 1.4717x; 1.0032x over previous
//
#include <hip/hip_runtime.h>
#include <hip/hip_bf16.h>
#include <math.h>

#define NA 2048
#define CP 16

// ===== Kernel A: stream plm -> bias[h][i][j] = LN(plm)@Wpb.T + beta (bf16) =====
__global__ __launch_bounds__(256) void bias_kernel(
    const float* __restrict__ plm, const float* __restrict__ beta_mask,
    const float* __restrict__ npw, const float* __restrict__ npb,
    const float* __restrict__ Wpb,
    __hip_bfloat16* __restrict__ biasT)
{
    const int t = threadIdx.x;
    const int quad = t & 3;            // channel-quad AND head id for the write
    const int jloc = t >> 2;           // 0..63
    const int jc = blockIdx.x & 31;
    const int ic = blockIdx.x >> 5;
    const int j = jc * 64 + jloc;
    const int i0 = ic * 8;

    float w0[4], w1[4], w2[4], w3[4];
    {
        const float4 a = *(const float4*)(Wpb + 0 * 16 + quad * 4);
        w0[0] = a.x; w0[1] = a.y; w0[2] = a.z; w0[3] = a.w;
        const float4 b = *(const float4*)(Wpb + 1 * 16 + quad * 4);
        w1[0] = b.x; w1[1] = b.y; w1[2] = b.z; w1[3] = b.w;
        const float4 c = *(const float4*)(Wpb + 2 * 16 + quad * 4);
        w2[0] = c.x; w2[1] = c.y; w2[2] = c.z; w2[3] = c.w;
        const float4 d = *(const float4*)(Wpb + 3 * 16 + quad * 4);
        w3[0] = d.x; w3[1] = d.y; w3[2] = d.z; w3[3] = d.w;
    }
    const float4 nw = *(const float4*)(npw + quad * 4);
    const float4 nb = *(const float4*)(npb + quad * 4);

#pragma unroll
    for (int ii = 0; ii < 8; ++ii) {
        const int i = i0 + ii;
        const float4 x = *(const float4*)(plm + ((size_t)i * NA + j) * CP + quad * 4);
        float s = x.x + x.y + x.z + x.w;
        float s2 = x.x * x.x + x.y * x.y + x.z * x.z + x.w * x.w;
        s += __shfl_xor(s, 1); s2 += __shfl_xor(s2, 1);
        s += __shfl_xor(s, 2); s2 += __shfl_xor(s2, 2);
        const float mu = s * 0.0625f;
        const float inv = rsqrtf(s2 * 0.0625f - mu * mu + 1e-5f);
        const float x0 = (x.x - mu) * inv * nw.x + nb.x;
        const float x1 = (x.y - mu) * inv * nw.y + nb.y;
        const float x2 = (x.z - mu) * inv * nw.z + nb.z;
        const float x3 = (x.w - mu) * inv * nw.w + nb.w;
        float p0 = x0 * w0[0] + x1 * w0[1] + x2 * w0[2] + x3 * w0[3];
        float p1 = x0 * w1[0] + x1 * w1[1] + x2 * w1[2] + x3 * w1[3];
        float p2 = x0 * w2[0] + x1 * w2[1] + x2 * w2[2] + x3 * w2[3];
        float p3 = x0 * w3[0] + x1 * w3[1] + x2 * w3[2] + x3 * w3[3];
        p0 += __shfl_xor(p0, 1); p1 += __shfl_xor(p1, 1);
        p2 += __shfl_xor(p2, 1); p3 += __shfl_xor(p3, 1);
        p0 += __shfl_xor(p0, 2); p1 += __shfl_xor(p1, 2);
        p2 += __shfl_xor(p2, 2); p3 += __shfl_xor(p3, 2);
        const float bm = beta_mask[(size_t)i * NA + j];
        const float sel = (quad == 0) ? p0 : (quad == 1) ? p1 : (quad == 2) ? p2 : p3;
        biasT[(size_t)quad * NA * NA + (size_t)i * NA + j] = __float2bfloat16(sel + bm);
    }
}

// ===== Kernel 1: LN(ql) + q/k/v/gate projections =====
__global__ __launch_bounds__(256) void qkvg_kernel(
    const float* __restrict__ ql,
    const float* __restrict__ nqw, const float* __restrict__ nqb,
    const float* __restrict__ Wq, const float* __restrict__ bq,
    const float* __restrict__ Wk, const float* __restrict__ Wv,
    const float* __restrict__ Wg,
    float* __restrict__ q_out, float* __restrict__ kT_out,
    float* __restrict__ vT_out, float* __restrict__ g_out)
{
    __shared__ float x_lds[4 * 128];
    __shared__ float xn_lds[4 * 128];
    const int t = threadIdx.x;
    const int row0 = blockIdx.x * 4;

    for (int idx = t; idx < 512; idx += 256)
        x_lds[idx] = ql[(size_t)row0 * 128 + idx];
    __syncthreads();

    if (t < 128) {
        const int r = t >> 5, id = t & 31;
        const float4 x4 = ((const float4*)x_lds)[r * 32 + id];
        float s = x4.x + x4.y + x4.z + x4.w;
        float s2 = x4.x * x4.x + x4.y * x4.y + x4.z * x4.z + x4.w * x4.w;
#pragma unroll
        for (int m = 16; m >= 1; m >>= 1) {
            s += __shfl_xor(s, m);
            s2 += __shfl_xor(s2, m);
        }
        const float mu = s * (1.0f / 128.0f);
        const float inv = rsqrtf(s2 * (1.0f / 128.0f) - mu * mu + 1e-5f);
#pragma unroll
        for (int k = 0; k < 4; ++k) {
            const int c = id * 4 + k;
            xn_lds[r * 128 + c] = (x_lds[r * 128 + c] - mu) * inv * nqw[c] + nqb[c];
        }
    }
    __syncthreads();

    const float4* xn4 = (const float4*)xn_lds;
#pragma unroll
    for (int cc = 0; cc < 2; ++cc) {
        const int col = cc * 256 + t;
        const int m = col >> 7;        // wave-uniform
        const int cl = col & 127;
        const float* W = (m == 0) ? Wq : (m == 1) ? Wk : (m == 2) ? Wv : Wg;
        float acc[4] = {0, 0, 0, 0};
        const float4* wrow = (const float4*)(W + (size_t)cl * 128);
#pragma unroll 8
        for (int k4 = 0; k4 < 32; ++k4) {
            const float4 w4 = wrow[k4];
#pragma unroll
            for (int r = 0; r < 4; ++r) {
                const float4 a = xn4[r * 32 + k4];
                acc[r] += a.x * w4.x + a.y * w4.y + a.z * w4.z + a.w * w4.w;
            }
        }
        if (m == 0) {
            const float bb = bq[cl];
            const float sc = 0.17677669529663687f; // 1/sqrt(32)
#pragma unroll
            for (int r = 0; r < 4; ++r)
                q_out[(size_t)(row0 + r) * 128 + cl] = (acc[r] + bb) * sc;
        } else if (m == 1) {
            float4 o; o.x = acc[0]; o.y = acc[1]; o.z = acc[2]; o.w = acc[3];
            *(float4*)(kT_out + (size_t)cl * NA + row0) = o;
        } else if (m == 2) {
            float4 o; o.x = acc[0]; o.y = acc[1]; o.z = acc[2]; o.w = acc[3];
            *(float4*)(vT_out + (size_t)cl * NA + row0) = o;
        } else {
#pragma unroll
            for (int r = 0; r < 4; ++r)
                g_out[(size_t)(row0 + r) * 128 + cl] = 1.0f / (1.0f + __expf(-acc[r]));
        }
    }
}

// ===== Kernel B: attention. Block = (head, 8 rows). QK: waves j-split.
// PV: wave owns 8 channels over ALL j -> v loads fully coalesced. =====
__global__ __launch_bounds__(256) void attn_kernel(
    const __hip_bfloat16* __restrict__ biasT,
    const float* __restrict__ q_ws, const float* __restrict__ kT,
    const float* __restrict__ vT, const float* __restrict__ g_ws,
    float* __restrict__ attn_g)
{
    __shared__ unsigned short Lp[8][2048];   // p (normalized) bf16: 32 KB
    __shared__ float q_s[8 * 32];
    __shared__ float redA[4 * 8];
    __shared__ float redB[4 * 8];

    const int t = threadIdx.x;
    const int h = blockIdx.x & 3;
    const int i0 = (blockIdx.x >> 2) * 8;
    const int w = t >> 6, lane = t & 63;
    const int jq = w * 512;

    q_s[t] = q_ws[(size_t)(i0 + (t >> 5)) * 128 + h * 32 + (t & 31)];
    __syncthreads();

    // init logits from bias(+beta)
    float4 La[8], Lb[8];
#pragma unroll
    for (int r = 0; r < 8; ++r) {
        const __hip_bfloat16* base = biasT + (size_t)h * NA * NA + (size_t)(i0 + r) * NA;
        const __hip_bfloat162* ba = (const __hip_bfloat162*)(base + jq + lane * 4);
        const float2 f0 = __bfloat1622float2(ba[0]);
        const float2 f1 = __bfloat1622float2(ba[1]);
        La[r] = make_float4(f0.x, f0.y, f1.x, f1.y);
        const __hip_bfloat162* bb = (const __hip_bfloat162*)(base + jq + 256 + lane * 4);
        const float2 g0 = __bfloat1622float2(bb[0]);
        const float2 g1 = __bfloat1622float2(bb[1]);
        Lb[r] = make_float4(g0.x, g0.y, g1.x, g1.y);
    }

    // QK: logits += q . k  (kT coalesced over j; q broadcast from LDS)
    const float* kb = kT + (size_t)(h * 32) * NA + jq + lane * 4;
#pragma unroll 4
    for (int c = 0; c < 32; ++c) {
        const float4 ka = *(const float4*)(kb + (size_t)c * NA);
        const float4 kc = *(const float4*)(kb + (size_t)c * NA + 256);
#pragma unroll
        for (int r = 0; r < 8; ++r) {
            const float qv = q_s[r * 32 + c];
            La[r].x += qv * ka.x; La[r].y += qv * ka.y;
            La[r].z += qv * ka.z; La[r].w += qv * ka.w;
            Lb[r].x += qv * kc.x; Lb[r].y += qv * kc.y;
            Lb[r].z += qv * kc.z; Lb[r].w += qv * kc.w;
        }
    }

    // softmax: wave-partial max -> combine -> exp -> wave-partial sum -> combine
#pragma unroll
    for (int r = 0; r < 8; ++r) {
        float m = fmaxf(fmaxf(fmaxf(La[r].x, La[r].y), fmaxf(La[r].z, La[r].w)),
                        fmaxf(fmaxf(Lb[r].x, Lb[r].y), fmaxf(Lb[r].z, Lb[r].w)));
#pragma unroll
        for (int mk = 32; mk >= 1; mk >>= 1) m = fmaxf(m, __shfl_xor(m, mk));
        if (lane == 0) redA[w * 8 + r] = m;
    }
    __syncthreads();
#pragma unroll
    for (int r = 0; r < 8; ++r) {
        const float m = fmaxf(fmaxf(redA[r], redA[8 + r]), fmaxf(redA[16 + r], redA[24 + r]));
        La[r].x = __expf(La[r].x - m); La[r].y = __expf(La[r].y - m);
        La[r].z = __expf(La[r].z - m); La[r].w = __expf(La[r].w - m);
        Lb[r].x = __expf(Lb[r].x - m); Lb[r].y = __expf(Lb[r].y - m);
        Lb[r].z = __expf(Lb[r].z - m); Lb[r].w = __expf(Lb[r].w - m);
        float s = La[r].x + La[r].y + La[r].z + La[r].w +
                  Lb[r].x + Lb[r].y + Lb[r].z + Lb[r].w;
#pragma unroll
        for (int mk = 32; mk >= 1; mk >>= 1) s += __shfl_xor(s, mk);
        if (lane == 0) redB[w * 8 + r] = s;
    }
    __syncthreads();
#pragma unroll
    for (int r = 0; r < 8; ++r) {
        const float invl = 1.0f / (redB[r] + redB[8 + r] + redB[16 + r] + redB[24 + r]);
        __hip_bfloat162* d = (__hip_bfloat162*)&Lp[r][jq + lane * 4];
        d[0] = __float22bfloat162_rn(make_float2(La[r].x * invl, La[r].y * invl));
        d[1] = __float22bfloat162_rn(make_float2(La[r].z * invl, La[r].w * invl));
        __hip_bfloat162* d2 = (__hip_bfloat162*)&Lp[r][jq + 256 + lane * 4];
        d2[0] = __float22bfloat162_rn(make_float2(Lb[r].x * invl, Lb[r].y * invl));
        d2[1] = __float22bfloat162_rn(make_float2(Lb[r].z * invl, Lb[r].w * invl));
    }
    __syncthreads();

    // PV: wave w owns channels c = w*8 .. w*8+7 over ALL j.
    // v loads lane-contiguous float4 (coalesced); p loaded once per jf, reused 8x.
    float o[8][8];   // [r][cc]
#pragma unroll
    for (int r = 0; r < 8; ++r)
#pragma unroll
        for (int cc = 0; cc < 8; ++cc) o[r][cc] = 0.0f;

    const float* vb0 = vT + (size_t)(h * 32 + w * 8) * NA;
#pragma unroll 2
    for (int jf = 0; jf < 8; ++jf) {
        const int joff = jf * 256 + lane * 4;
        float2 pa[8], pb[8];
#pragma unroll
        for (int r = 0; r < 8; ++r) {
            const __hip_bfloat162* pp = (const __hip_bfloat162*)&Lp[r][joff];
            pa[r] = __bfloat1622float2(pp[0]);
            pb[r] = __bfloat1622float2(pp[1]);
        }
#pragma unroll
        for (int cc = 0; cc < 8; ++cc) {
            const float4 v4 = *(const float4*)(vb0 + (size_t)cc * NA + joff);
#pragma unroll
            for (int r = 0; r < 8; ++r) {
                o[r][cc] += pa[r].x * v4.x + pa[r].y * v4.y +
                            pb[r].x * v4.z + pb[r].y * v4.w;
            }
        }
    }

    // reduce across lanes: 3-stage xor -> 8 partials per (r,cc), stash in LDS
    __syncthreads();                 // all Lp reads done; reuse its space
    float* op = (float*)&Lp[0][0];   // [w*8+r][cc][8] = 2048 floats
#pragma unroll
    for (int r = 0; r < 8; ++r) {
#pragma unroll
        for (int cc = 0; cc < 8; ++cc) {
            float s = o[r][cc];
            s += __shfl_xor(s, 32);
            s += __shfl_xor(s, 16);
            s += __shfl_xor(s, 8);
            o[r][cc] = s;            // lanes sharing low-3-bits now hold group sum
        }
    }
    if (lane < 8) {
#pragma unroll
        for (int r = 0; r < 8; ++r)
#pragma unroll
            for (int cc = 0; cc < 8; ++cc)
                op[((w * 8 + r) * 8 + cc) * 8 + lane] = o[r][cc];
    }
    __syncthreads();

    // final: thread t = ((w2*8 + r)*8 + cc); sum 8 partials, gate, store
    {
        const float4 a = ((const float4*)op)[t * 2];
        const float4 b = ((const float4*)op)[t * 2 + 1];
        const float s = a.x + a.y + a.z + a.w + b.x + b.y + b.z + b.w;
        const int r = (t >> 3) & 7;
        const int c = (t >> 6) * 8 + (t & 7);
        const float g = g_ws[(size_t)(i0 + r) * 128 + h * 32 + c];
        attn_g[(size_t)(i0 + r) * 128 + h * 32 + c] = s * g;
    }
}

// ===== Kernel 3: Wo proj + residual + LN + MLP + residual =====
__global__ __launch_bounds__(256) void out_mlp_kernel(
    const float* __restrict__ ql,
    const float* __restrict__ attn_g,
    const float* __restrict__ Wo,
    const float* __restrict__ tlw, const float* __restrict__ tlb,
    const float* __restrict__ W1, const float* __restrict__ b1,
    const float* __restrict__ W2, const float* __restrict__ b2,
    float* __restrict__ out)
{
    __shared__ float a_lds[4 * 128];
    __shared__ float ql2_lds[4 * 128];
    __shared__ float t_lds[4 * 128];
    __shared__ float h1_lds[4 * 512];
    const int t = threadIdx.x;
    const int row0 = blockIdx.x * 4;

    for (int idx = t; idx < 512; idx += 256)
        a_lds[idx] = attn_g[(size_t)row0 * 128 + idx];
    __syncthreads();

    // Stage 1: ql2 = ql + a @ Wo.T ; col = t/2, k-half = t&1
    {
        const int col = t >> 1, kh = t & 1;
        float p[4] = {0, 0, 0, 0};
        const float4* wr = (const float4*)(Wo + (size_t)col * 128 + kh * 64);
        const float4* a4 = (const float4*)a_lds;
#pragma unroll 8
        for (int k4 = 0; k4 < 16; ++k4) {
            const float4 w4 = wr[k4];
#pragma unroll
            for (int r = 0; r < 4; ++r) {
                const float4 a = a4[r * 32 + kh * 16 + k4];
                p[r] += a.x * w4.x + a.y * w4.y + a.z * w4.z + a.w * w4.w;
            }
        }
#pragma unroll
        for (int r = 0; r < 4; ++r) p[r] += __shfl_xor(p[r], 1);
        if (kh == 0) {
#pragma unroll
            for (int r = 0; r < 4; ++r)
                ql2_lds[r * 128 + col] = ql[(size_t)(row0 + r) * 128 + col] + p[r];
        }
    }
    __syncthreads();

    // LayerNorm(ql2) -> t_lds
    if (t < 128) {
        const int r = t >> 5, id = t & 31;
        const float4 x4 = ((const float4*)ql2_lds)[r * 32 + id];
        float s = x4.x + x4.y + x4.z + x4.w;
        float s2 = x4.x * x4.x + x4.y * x4.y + x4.z * x4.z + x4.w * x4.w;
#pragma unroll
        for (int m = 16; m >= 1; m >>= 1) {
            s += __shfl_xor(s, m);
            s2 += __shfl_xor(s2, m);
        }
        const float mu = s * (1.0f / 128.0f);
        const float inv = rsqrtf(s2 * (1.0f / 128.0f) - mu * mu + 1e-5f);
#pragma unroll
        for (int k = 0; k < 4; ++k) {
            const int c = id * 4 + k;
            t_lds[r * 128 + c] = (ql2_lds[r * 128 + c] - mu) * inv * tlw[c] + tlb[c];
        }
    }
    __syncthreads();

    // Stage 2: h1 = relu(t @ W1.T + b1), 2 cols/thread, full K
    const float4* t4 = (const float4*)t_lds;
#pragma unroll
    for (int cc = 0; cc < 2; ++cc) {
        const int col = cc * 256 + t;
        float acc[4] = {0, 0, 0, 0};
        const float4* wr = (const float4*)(W1 + (size_t)col * 128);
#pragma unroll 8
        for (int k4 = 0; k4 < 32; ++k4) {
            const float4 w4 = wr[k4];
#pragma unroll
            for (int r = 0; r < 4; ++r) {
                const float4 a = t4[r * 32 + k4];
                acc[r] += a.x * w4.x + a.y * w4.y + a.z * w4.z + a.w * w4.w;
            }
        }
        const float bb = b1[col];
#pragma unroll
        for (int r = 0; r < 4; ++r)
            h1_lds[r * 512 + col] = fmaxf(acc[r] + bb, 0.0f);
    }
    __syncthreads();

    // Stage 3: out = ql2 + h1 @ W2.T + b2 ; col = t/2, k-half = t&1 (K=512)
    {
        const int col = t >> 1, kh = t & 1;
        float p[4] = {0, 0, 0, 0};
        const float4* wr = (const float4*)(W2 + (size_t)col * 512 + kh * 256);
        const float4* h4 = (const float4*)h1_lds;
#pragma unroll 8
        for (int k4 = 0; k4 < 64; ++k4) {
            const float4 w4 = wr[k4];
#pragma unroll
            for (int r = 0; r < 4; ++r) {
                const float4 a = h4[r * 128 + kh * 64 + k4];
                p[r] += a.x * w4.x + a.y * w4.y + a.z * w4.z + a.w * w4.w;
            }
        }
#pragma unroll
        for (int r = 0; r < 4; ++r) p[r] += __shfl_xor(p[r], 1);
        if (kh == 0) {
            const float bb = b2[col];
#pragma unroll
            for (int r = 0; r < 4; ++r)
                out[(size_t)(row0 + r) * 128 + col] = ql2_lds[r * 128 + col] + p[r] + bb;
        }
    }
}

extern "C" void kernel_launch(void* const* d_in, const int* in_sizes, int n_in,
                              void* d_out, int out_size, void* d_ws, size_t ws_size,
                              hipStream_t stream) {
    const float* ql   = (const float*)d_in[0];
    // d_in[1] = cl : unused by the reference
    const float* plm  = (const float*)d_in[2];
    const float* beta = (const float*)d_in[3];
    const float* nqw  = (const float*)d_in[4];
    const float* nqb  = (const float*)d_in[5];
    const float* npw  = (const float*)d_in[6];
    const float* npb  = (const float*)d_in[7];
    const float* Wq   = (const float*)d_in[8];
    const float* bq   = (const float*)d_in[9];
    const float* Wk   = (const float*)d_in[10];
    const float* Wv   = (const float*)d_in[11];
    const float* Wpb  = (const float*)d_in[12];
    const float* Wg   = (const float*)d_in[13];
    const float* Wo   = (const float*)d_in[14];
    const float* tlw  = (const float*)d_in[15];
    const float* tlb  = (const float*)d_in[16];
    const float* W1   = (const float*)d_in[17];
    const float* b1   = (const float*)d_in[18];
    const float* W2   = (const float*)d_in[19];
    const float* b2   = (const float*)d_in[20];
    float* out = (float*)d_out;

    // workspace layout (bytes): bias bf16 33.5 MB, then 5 fp32 1-MB buffers
    char* ws = (char*)d_ws;
    __hip_bfloat16* biasT = (__hip_bfloat16*)ws;                  // 4*2048*2048*2
    float* q_ws  = (float*)(ws + 33554432);
    float* g_ws  = (float*)(ws + 33554432 + 1 * 1048576);
    float* kT_ws = (float*)(ws + 33554432 + 2 * 1048576);
    float* vT_ws = (float*)(ws + 33554432 + 3 * 1048576);
    float* ag_ws = (float*)(ws + 33554432 + 4 * 1048576);

    bias_kernel<<<8192, 256, 0, stream>>>(plm, beta, npw, npb, Wpb, biasT);
    qkvg_kernel<<<NA / 4, 256, 0, stream>>>(ql, nqw, nqb, Wq, bq, Wk, Wv, Wg,
                                            q_ws, kT_ws, vT_ws, g_ws);
    attn_kernel<<<NA / 2, 256, 0, stream>>>(biasT, q_ws, kT_ws, vT_ws, g_ws, ag_ws);
    out_mlp_kernel<<<NA / 4, 256, 0, stream>>>(ql, ag_ws, Wo, tlw, tlb,
                                               W1, b1, W2, b2, out);
}